// Round 23
// baseline (44.735 us; speedup 1.0000x reference)
//
#include <hip/hip_runtime.h>
#include <hip/hip_bf16.h>

#define BN   8
#define NN   1024
#define CIN  256
#define COUT 256
#define HH   4
#define CC   64
#define ALPHA_C 0.2f

typedef __attribute__((ext_vector_type(8))) short short8;
typedef __attribute__((ext_vector_type(4))) float f32x4;

__device__ __forceinline__ unsigned short f2bf(float x) {
    __hip_bfloat16 h = __float2bfloat16(x);
    return *(unsigned short*)&h;
}
__device__ __forceinline__ float bf2f(unsigned short u) {
    return __uint_as_float(((unsigned int)u) << 16);
}
__device__ __forceinline__ void gl_lds16(const void* g, void* l) {
    __builtin_amdgcn_global_load_lds(
        (const __attribute__((address_space(1))) void*)g,
        (__attribute__((address_space(3))) void*)l, 16, 0, 0);
}

// ---------------- Kernel W: pack W (fp32) -> Wh/Wl bf16 panels -----------------------
__global__ __launch_bounds__(256) void kw_pack(
    const float* __restrict__ W, unsigned short* __restrict__ Whp, unsigned short* __restrict__ Wlp)
{
    const int bid = blockIdx.x;          // kc*4 + jg
    const int n = threadIdx.x;
    const int fi = n * 64 + (bid >> 2) * 8 + (bid & 3) * 2;
    const float4* W4 = (const float4*)W;
    float4 wa = W4[fi], wb = W4[fi + 1];
    float xs[8] = {wa.x, wa.y, wa.z, wa.w, wb.x, wb.y, wb.z, wb.w};
    unsigned short hh[8], ll[8];
    #pragma unroll
    for (int e = 0; e < 8; ++e) {
        hh[e] = f2bf(xs[e]);
        ll[e] = f2bf(xs[e] - bf2f(hh[e]));
    }
    *(uint4*)(Whp + ((size_t)bid * 256 + n) * 8) = *(uint4*)hh;
    *(uint4*)(Wlp + ((size_t)bid * 256 + n) * 8) = *(uint4*)ll;
}

// ---------------- Kernel 1x: GEMM blocks (0..255) + adj-pack blocks (256..767) -------
// The adj bitmap is consumed only by k2, so its 5.3 us HBM stream rides CONCURRENTLY
// with the GEMM: 512 adj blocks (no LDS) fill scheduler slots around the 256 GEMM
// blocks instead of serializing as a separate kernel (r20's kprep-adj).
__global__ __launch_bounds__(1024, 1) void k1x(
    const float* __restrict__ X, const float* __restrict__ bias, const float* __restrict__ a,
    const int* __restrict__ adj, const unsigned short* __restrict__ Whp,
    const unsigned short* __restrict__ Wlp, unsigned short* __restrict__ hbf_p,
    float* __restrict__ lsrc_t, float* __restrict__ ldst_t, unsigned int* __restrict__ bmG)
{
    const int tid = threadIdx.x;
    const int wv = tid >> 6, l = tid & 63;

    if (blockIdx.x >= 256) {
        // ---- adj bit-pack: block a = bid-256 packs 16 rows (wave wv -> one row) ----
        const int a_ = blockIdx.x - 256;
        const int b  = a_ & 7;                 // XCD-aligned with consumer k2
        const int ch = a_ >> 3;                // 0..63
        const int row = b * NN + ch * 16 + wv;
        const int* arow = adj + (size_t)row * NN;
        #pragma unroll 4
        for (int it = 0; it < 16; ++it) {
            int av = arow[it * 64 + l];
            unsigned long long mb = __ballot(av != 0);
            if (l == 0) {
                bmG[(size_t)row * 32 + 2 * it    ] = (unsigned int)mb;
                bmG[(size_t)row * 32 + 2 * it + 1] = (unsigned int)(mb >> 32);
            }
        }
        return;
    }

    // ---- GEMM block (r20 body, unchanged) ----
    __shared__ __align__(16) unsigned short Xh[32 * 256];   // 16 KB, XOR-swizzled
    __shared__ __align__(16) unsigned short Xl[32 * 256];   // 16 KB
    __shared__ float lsP[2][8][2][16];                      // [src/dst][no][mq][m16]

    const int bid = blockIdx.x;
    const int b  = bid & 7;
    const int tj = bid >> 3;
    const int row0 = b * NN + tj * 32;
    const int il = l & 15, jg = l >> 4;
    const int mq = wv >> 3, no = wv & 7;

    {
        const float4* X4 = (const float4*)(X + (size_t)row0 * CIN);
        #pragma unroll
        for (int it = 0; it < 2; ++it) {
            int f = it * 1024 + tid;            // 0..2047 (32 rows x 64 float4)
            int r = f >> 6, k4 = f & 63;
            float4 x = X4[f];
            unsigned short h0 = f2bf(x.x), h1 = f2bf(x.y), h2 = f2bf(x.z), h3 = f2bf(x.w);
            unsigned short l0 = f2bf(x.x - bf2f(h0)), l1 = f2bf(x.y - bf2f(h1));
            unsigned short l2 = f2bf(x.z - bf2f(h2)), l3 = f2bf(x.w - bf2f(h3));
            unsigned short hs[4] = {h0, h1, h2, h3}, ls[4] = {l0, l1, l2, l3};
            int off = r * 512 + ((k4 * 8) ^ ((r & 7) << 4));
            *(uint2*)((char*)Xh + off) = *(uint2*)hs;
            *(uint2*)((char*)Xl + off) = *(uint2*)ls;
        }
    }
    __syncthreads();

    f32x4 acc0 = {0.f, 0.f, 0.f, 0.f}, acc1 = acc0;
    {
        const int abase = (mq * 16 + il) * 512;
        const int swz = (il & 7) << 4;
        const short8* Wh8 = (const short8*)Whp;
        const short8* Wl8 = (const short8*)Wlp;
        const int nb = no * 32 + il;
        #pragma unroll
        for (int kc = 0; kc < 8; ++kc) {
            const int ab = abase + ((kc * 64 + jg * 16) ^ swz);
            short8 Ah = *(const short8*)((const char*)Xh + ab);
            short8 Al = *(const short8*)((const char*)Xl + ab);
            const int pidx = (kc * 4 + jg) * 256 + nb;
            short8 Bh0 = Wh8[pidx],      Bl0 = Wl8[pidx];
            short8 Bh1 = Wh8[pidx + 16], Bl1 = Wl8[pidx + 16];
            acc0 = __builtin_amdgcn_mfma_f32_16x16x32_bf16(Ah, Bh0, acc0, 0, 0, 0);
            acc1 = __builtin_amdgcn_mfma_f32_16x16x32_bf16(Ah, Bh1, acc1, 0, 0, 0);
            acc0 = __builtin_amdgcn_mfma_f32_16x16x32_bf16(Ah, Bl0, acc0, 0, 0, 0);
            acc1 = __builtin_amdgcn_mfma_f32_16x16x32_bf16(Ah, Bl1, acc1, 0, 0, 0);
            acc0 = __builtin_amdgcn_mfma_f32_16x16x32_bf16(Al, Bh0, acc0, 0, 0, 0);
            acc1 = __builtin_amdgcn_mfma_f32_16x16x32_bf16(Al, Bh1, acc1, 0, 0, 0);
        }
    }

    const int c0 = no * 32 + il, c1 = c0 + 16;
    const float bia0 = bias[c0], bia1 = bias[c1];
    const int hh = no >> 1;
    const int cc0 = c0 & 63, cc1 = c1 & 63;
    const float as0 = a[hh * 128 + cc0],      as1 = a[hh * 128 + cc1];
    const float ad0 = a[hh * 128 + 64 + cc0], ad1 = a[hh * 128 + 64 + cc1];

    float v0[4], v1[4], psrc[4], pdst[4];
    #pragma unroll
    for (int r = 0; r < 4; ++r) {
        v0[r] = acc0[r] + bia0;
        v1[r] = acc1[r] + bia1;
        psrc[r] = v0[r] * as0 + v1[r] * as1;
        pdst[r] = v0[r] * ad0 + v1[r] * ad1;
    }
    #pragma unroll
    for (int off = 8; off >= 1; off >>= 1) {
        #pragma unroll
        for (int r = 0; r < 4; ++r) {
            psrc[r] += __shfl_xor(psrc[r], off);
            pdst[r] += __shfl_xor(pdst[r], off);
        }
    }
    __syncthreads();   // all waves done reading Xh/Xl

    unsigned short* hp = Xh;
    #pragma unroll
    for (int r = 0; r < 4; ++r) {
        int m = mq * 16 + 4 * jg + r;
        int base = (m >> 3) * 128 + (m & 7);
        hp[(c0 >> 6) * 2048 + ((c0 & 63) >> 4) * 512 + base + (c0 & 15) * 8] = f2bf(v0[r]);
        hp[(c1 >> 6) * 2048 + ((c1 & 63) >> 4) * 512 + base + (c1 & 15) * 8] = f2bf(v1[r]);
    }
    if (il == 0) {
        #pragma unroll
        for (int r = 0; r < 4; ++r) {
            lsP[0][no][mq][4 * jg + r] = psrc[r];
            lsP[1][no][mq][4 * jg + r] = pdst[r];
        }
    }
    __syncthreads();

    {
        uint4* dst4 = (uint4*)(hbf_p + (size_t)(b * 32 + tj) * 8192);
        dst4[tid] = ((const uint4*)hp)[tid];
    }
    if (tid < 256) {
        int sd = tid >> 7, rem = tid & 127, h2 = rem >> 5, m = rem & 31;
        float v = lsP[sd][2 * h2][m >> 4][m & 15] + lsP[sd][2 * h2 + 1][m >> 4][m & 15];
        float* dst = sd ? ldst_t : lsrc_t;
        dst[((size_t)b * HH + h2) * NN + tj * 32 + m] = v;
    }
}

// ---------------- Kernel 2: masked softmax attention, PV via MFMA, LDS-resident -----
// r20's best-measured k2, byte-identical (diet variants of r21/r22 regressed).
__global__ __launch_bounds__(1024, 1) void k2_attn(
    const unsigned short* __restrict__ hbf_p, const unsigned int* __restrict__ bmG,
    const float* __restrict__ lsrc_t, const float* __restrict__ ldst_t,
    float* __restrict__ out)
{
    __shared__ __align__(16) char smem[151808];
    // [0, 131072)        hS: head panels, short8 idx tj*256 + cs*64 + l  (epi: red[2][128][68] f32)
    // [131072, 147712)   bmS: u32 [32 tj][130 pad]
    // [147712, 151808)   ldstS: f32 [1024]
    __shared__ float lsumS[4][4][32];     // [jq][rg][row32]

    unsigned short* hS  = (unsigned short*)smem;
    unsigned int*  bmS  = (unsigned int*)(smem + 131072);
    float*        ldstS = (float*)(smem + 147712);

    const int bid = blockIdx.x;
    const int b  = bid & 7;
    const int h  = (bid >> 3) & 3;
    const int i0 = (bid >> 5) * 128;
    const int tid = threadIdx.x;
    const int wv = tid >> 6, l = tid & 63, il = l & 15, jg = l >> 4;
    const int rg = wv >> 2, jq = wv & 3;

    // ---- stage head panel-set via global_load_lds (local L2) ----
    {
        #pragma unroll
        for (int k = 0; k < 2; ++k) {
            const int tj = wv * 2 + k;
            #pragma unroll
            for (int cs = 0; cs < 4; ++cs) {
                gl_lds16(hbf_p + ((((size_t)(b * 32 + tj)) * 1024 + h * 256 + cs * 64 + l) << 3),
                         hS + (size_t)(tj * 256 + cs * 64 + l) * 8);
            }
        }
    }
    // ---- stage bitmap [row][word] -> bmS[word][row] ----
    {
        const unsigned int* bsrc = bmG + ((size_t)(b * NN + i0)) * 32;
        #pragma unroll
        for (int k = 0; k < 4; ++k) {
            int idx = k * 1024 + tid;          // 0..4095
            int r = idx >> 5, w = idx & 31;
            bmS[w * 130 + r] = bsrc[idx];
        }
    }
    // ---- stage ldst table for this head ----
    if (tid < 256)
        ((float4*)ldstS)[tid] = ((const float4*)(ldst_t + ((size_t)(b * HH + h)) * NN))[tid];

    const float* lsrc_b = lsrc_t + ((size_t)(b * HH + h)) * NN + i0 + rg * 32;
    const float lsv0 = lsrc_b[il];
    const float lsv1 = lsrc_b[16 + il];

    __syncthreads();   // staging drained (gl_lds vmcnt included)

    // ---- mx = max over all j of ldst[h] (valid softmax shift: lrelu monotone) ----
    float mx = -3.4e38f;
    #pragma unroll
    for (int jt = 0; jt < 16; ++jt) mx = fmaxf(mx, ldstS[jt * 64 + l]);
    #pragma unroll
    for (int off = 32; off >= 1; off >>= 1) mx = fmaxf(mx, __shfl_xor(mx, off));
    float mr0, mr1;
    { float t_ = lsv0 + mx; mr0 = fmaxf(t_, ALPHA_C * t_); }
    { float t_ = lsv1 + mx; mr1 = fmaxf(t_, ALPHA_C * t_); }
    float ls0 = 0.f, ls1 = 0.f;

    f32x4 z4 = {0.f,0.f,0.f,0.f};
    f32x4 a00 = z4, a01 = z4, a02 = z4, a03 = z4;   // rows rg*32..+15
    f32x4 a10 = z4, a11 = z4, a12 = z4, a13 = z4;   // rows rg*32+16..+31

    const short8* hS8 = (const short8*)hS;

    // ---- hot loop: 8 panels, pure LDS + VALU + MFMA; c-frags reused by 2 rowgroups ----
    #pragma unroll 2
    for (int t = 0; t < 8; ++t) {
        const int tj = jq * 8 + t;
        short8 c0 = hS8[tj * 256 +   0 + l];
        short8 c1 = hS8[tj * 256 +  64 + l];
        short8 c2 = hS8[tj * 256 + 128 + l];
        short8 c3 = hS8[tj * 256 + 192 + l];
        const unsigned int bw0 = bmS[tj * 130 + rg * 32 + il] >> (jg * 8);
        const unsigned int bw1 = bmS[tj * 130 + rg * 32 + 16 + il] >> (jg * 8);
        const float4 dA = *(const float4*)(ldstS + tj * 32 + jg * 8);
        const float4 dB = *(const float4*)(ldstS + tj * 32 + jg * 8 + 4);

        short8 af0, af1;
        #define PELEM(AF, E, DV, BWV, LSV, MR, LS) {             \
            float s_ = (LSV) + (DV);                             \
            s_ = fmaxf(s_, ALPHA_C * s_);                        \
            float p_ = __expf(s_ - (MR));                        \
            p_ = ((BWV >> (E)) & 1u) ? p_ : 0.f;                 \
            LS += p_;                                            \
            AF[E] = (short)(__float_as_uint(p_) >> 16); }
        PELEM(af0, 0, dA.x, bw0, lsv0, mr0, ls0)
        PELEM(af0, 1, dA.y, bw0, lsv0, mr0, ls0)
        PELEM(af0, 2, dA.z, bw0, lsv0, mr0, ls0)
        PELEM(af0, 3, dA.w, bw0, lsv0, mr0, ls0)
        PELEM(af0, 4, dB.x, bw0, lsv0, mr0, ls0)
        PELEM(af0, 5, dB.y, bw0, lsv0, mr0, ls0)
        PELEM(af0, 6, dB.z, bw0, lsv0, mr0, ls0)
        PELEM(af0, 7, dB.w, bw0, lsv0, mr0, ls0)
        PELEM(af1, 0, dA.x, bw1, lsv1, mr1, ls1)
        PELEM(af1, 1, dA.y, bw1, lsv1, mr1, ls1)
        PELEM(af1, 2, dA.z, bw1, lsv1, mr1, ls1)
        PELEM(af1, 3, dA.w, bw1, lsv1, mr1, ls1)
        PELEM(af1, 4, dB.x, bw1, lsv1, mr1, ls1)
        PELEM(af1, 5, dB.y, bw1, lsv1, mr1, ls1)
        PELEM(af1, 6, dB.z, bw1, lsv1, mr1, ls1)
        PELEM(af1, 7, dB.w, bw1, lsv1, mr1, ls1)
        #undef PELEM

        a00 = __builtin_amdgcn_mfma_f32_16x16x32_bf16(af0, c0, a00, 0, 0, 0);
        a01 = __builtin_amdgcn_mfma_f32_16x16x32_bf16(af0, c1, a01, 0, 0, 0);
        a02 = __builtin_amdgcn_mfma_f32_16x16x32_bf16(af0, c2, a02, 0, 0, 0);
        a03 = __builtin_amdgcn_mfma_f32_16x16x32_bf16(af0, c3, a03, 0, 0, 0);
        a10 = __builtin_amdgcn_mfma_f32_16x16x32_bf16(af1, c0, a10, 0, 0, 0);
        a11 = __builtin_amdgcn_mfma_f32_16x16x32_bf16(af1, c1, a11, 0, 0, 0);
        a12 = __builtin_amdgcn_mfma_f32_16x16x32_bf16(af1, c2, a12, 0, 0, 0);
        a13 = __builtin_amdgcn_mfma_f32_16x16x32_bf16(af1, c3, a13, 0, 0, 0);
    }

    // ---- lsum partials (this jq): reduce over jg, stash ----
    ls0 += __shfl_xor(ls0, 16); ls0 += __shfl_xor(ls0, 32);
    ls1 += __shfl_xor(ls1, 16); ls1 += __shfl_xor(ls1, 32);
    if (l < 16) {
        lsumS[jq][rg][il] = ls0;
        lsumS[jq][rg][16 + il] = ls1;
    }
    __syncthreads();   // hot-loop LDS reads done; red may overlay hS

    // ---- 2-phase RMW over jq into red[2][128 rows][68 pad] ----
    float* red0 = (float*)smem;
    float* red1 = red0 + 128 * 68;
    {
        float* rb = (jq & 1) ? red1 : red0;
        const int rbase = rg * 32 + 4 * jg;
        #define STROW(ACC, ROFF, CS, OP) {                                   \
            rb[(rbase + (ROFF) + 0) * 68 + (CS) * 16 + il] OP ACC[0];        \
            rb[(rbase + (ROFF) + 1) * 68 + (CS) * 16 + il] OP ACC[1];        \
            rb[(rbase + (ROFF) + 2) * 68 + (CS) * 16 + il] OP ACC[2];        \
            rb[(rbase + (ROFF) + 3) * 68 + (CS) * 16 + il] OP ACC[3]; }
        #define STOREALL(OP) {                                               \
            STROW(a00, 0, 0, OP) STROW(a01, 0, 1, OP)                        \
            STROW(a02, 0, 2, OP) STROW(a03, 0, 3, OP)                        \
            STROW(a10, 16, 0, OP) STROW(a11, 16, 1, OP)                      \
            STROW(a12, 16, 2, OP) STROW(a13, 16, 3, OP) }
        if (jq < 2) STOREALL(=)
        __syncthreads();
        if (jq >= 2) STOREALL(+=)
        __syncthreads();
        #undef STROW
        #undef STOREALL
    }

    // ---- final: sum red pair, normalize, float4 store ----
    #pragma unroll
    for (int pass = 0; pass < 2; ++pass) {
        int row = pass * 64 + (tid >> 4);
        int c4  = tid & 15;
        float4 v0 = *(const float4*)(red0 + row * 68 + c4 * 4);
        float4 v1 = *(const float4*)(red1 + row * 68 + c4 * 4);
        float ls = lsumS[0][row >> 5][row & 31] + lsumS[1][row >> 5][row & 31]
                 + lsumS[2][row >> 5][row & 31] + lsumS[3][row >> 5][row & 31];
        float inv = 1.0f / ls;
        float4 o = make_float4((v0.x + v1.x) * inv, (v0.y + v1.y) * inv,
                               (v0.z + v1.z) * inv, (v0.w + v1.w) * inv);
        *(float4*)(out + ((size_t)(b * NN + i0 + row)) * COUT + h * 64 + c4 * 4) = o;
    }
}

extern "C" void kernel_launch(void* const* d_in, const int* in_sizes, int n_in,
                              void* d_out, int out_size, void* d_ws, size_t ws_size,
                              hipStream_t stream) {
    const float* X    = (const float*)d_in[0];
    const int*   adj  = (const int*)  d_in[1];
    const float* W    = (const float*)d_in[2];
    const float* bias = (const float*)d_in[3];
    const float* a    = (const float*)d_in[4];
    float* out = (float*)d_out;

    unsigned short* hbf_p = (unsigned short*)d_ws;                  // 8*32 panels, 4 MB
    float* lsrc_t = (float*)(hbf_p + (size_t)BN * 32 * 8192);       // [b][h][n]
    float* ldst_t = lsrc_t + (size_t)BN * HH * NN;
    unsigned short* Whp = (unsigned short*)(ldst_t + (size_t)BN * HH * NN);  // 128 KB
    unsigned short* Wlp = Whp + 65536;                                        // 128 KB
    unsigned int*   bmG = (unsigned int*)(Wlp + 65536);                       // 1 MB bitmap

    kw_pack<<<32, 256, 0, stream>>>(W, Whp, Wlp);
    k1x<<<256 + 512, 1024, 0, stream>>>(X, bias, a, adj, Whp, Wlp, hbf_p, lsrc_t, ldst_t, bmG);
    k2_attn<<<256, 1024, 0, stream>>>(hbf_p, bmG, lsrc_t, ldst_t, out);
}

// Round 24
// 41.484 us; speedup vs baseline: 1.0784x; 1.0784x over previous
//
#include <hip/hip_runtime.h>
#include <hip/hip_bf16.h>

#define BN   8
#define NN   1024
#define CIN  256
#define COUT 256
#define HH   4
#define CC   64
#define ALPHA_C 0.2f

typedef __attribute__((ext_vector_type(8))) short short8;
typedef __attribute__((ext_vector_type(4))) float f32x4;

__device__ __forceinline__ unsigned short f2bf(float x) {
    __hip_bfloat16 h = __float2bfloat16(x);
    return *(unsigned short*)&h;
}
__device__ __forceinline__ float bf2f(unsigned short u) {
    return __uint_as_float(((unsigned int)u) << 16);
}
__device__ __forceinline__ void gl_lds16(const void* g, void* l) {
    __builtin_amdgcn_global_load_lds(
        (const __attribute__((address_space(1))) void*)g,
        (__attribute__((address_space(3))) void*)l, 16, 0, 0);
}

// ---------------- Kernel P: fused W-pack + adj-bitmap-pack (independent works) -------
// bid < 2048: adj pack (XCD-aligned: b = bid&7). bid >= 2048: W pack (32 blocks).
__global__ __launch_bounds__(256) void kprep(
    const float* __restrict__ W, const int* __restrict__ adj,
    unsigned short* __restrict__ Whp, unsigned short* __restrict__ Wlp,
    unsigned int* __restrict__ bmG)
{
    if (blockIdx.x < 2048) {
        const int bid = blockIdx.x;
        const int b  = bid & 7;
        const int rl = bid >> 3;                    // 0..255
        const int wv = threadIdx.x >> 6;
        const int l  = threadIdx.x & 63;
        const int row = b * NN + rl * 4 + wv;
        const int* arow = adj + (size_t)row * NN;
        #pragma unroll 4
        for (int it = 0; it < 16; ++it) {
            int av = arow[it * 64 + l];
            unsigned long long mb = __ballot(av != 0);
            if (l == 0) {
                bmG[row * 32 + 2 * it    ] = (unsigned int)mb;
                bmG[row * 32 + 2 * it + 1] = (unsigned int)(mb >> 32);
            }
        }
    } else {
        const int bid = blockIdx.x - 2048;          // kc*4 + jg
        const int n = threadIdx.x;
        const int fi = n * 64 + (bid >> 2) * 8 + (bid & 3) * 2;
        const float4* W4 = (const float4*)W;
        float4 wa = W4[fi], wb = W4[fi + 1];
        float xs[8] = {wa.x, wa.y, wa.z, wa.w, wb.x, wb.y, wb.z, wb.w};
        unsigned short hh[8], ll[8];
        #pragma unroll
        for (int e = 0; e < 8; ++e) {
            hh[e] = f2bf(xs[e]);
            ll[e] = f2bf(xs[e] - bf2f(hh[e]));
        }
        *(uint4*)(Whp + ((size_t)bid * 256 + n) * 8) = *(uint4*)hh;
        *(uint4*)(Wlp + ((size_t)bid * 256 + n) * 8) = *(uint4*)ll;
    }
}

// ---------------- Kernel 1: h = X@W^T + b via bf16x3 MFMA, XCD-aligned ----------------
__global__ __launch_bounds__(1024, 1) void k1_gemm(
    const float* __restrict__ X, const float* __restrict__ bias, const float* __restrict__ a,
    const unsigned short* __restrict__ Whp, const unsigned short* __restrict__ Wlp,
    unsigned short* __restrict__ hbf_p, float* __restrict__ lsrc_t, float* __restrict__ ldst_t)
{
    __shared__ __align__(16) unsigned short Xh[32 * 256];   // 16 KB, XOR-swizzled
    __shared__ __align__(16) unsigned short Xl[32 * 256];   // 16 KB
    __shared__ float lsP[2][8][2][16];                      // [src/dst][no][mq][m16]

    const int bid = blockIdx.x;
    const int b  = bid & 7;
    const int tj = bid >> 3;
    const int row0 = b * NN + tj * 32;
    const int tid = threadIdx.x;
    const int wv = tid >> 6, l = tid & 63, il = l & 15, jg = l >> 4;
    const int mq = wv >> 3, no = wv & 7;

    {
        const float4* X4 = (const float4*)(X + (size_t)row0 * CIN);
        #pragma unroll
        for (int it = 0; it < 2; ++it) {
            int f = it * 1024 + tid;            // 0..2047 (32 rows x 64 float4)
            int r = f >> 6, k4 = f & 63;
            float4 x = X4[f];
            unsigned short h0 = f2bf(x.x), h1 = f2bf(x.y), h2 = f2bf(x.z), h3 = f2bf(x.w);
            unsigned short l0 = f2bf(x.x - bf2f(h0)), l1 = f2bf(x.y - bf2f(h1));
            unsigned short l2 = f2bf(x.z - bf2f(h2)), l3 = f2bf(x.w - bf2f(h3));
            unsigned short hs[4] = {h0, h1, h2, h3}, ls[4] = {l0, l1, l2, l3};
            int off = r * 512 + ((k4 * 8) ^ ((r & 7) << 4));
            *(uint2*)((char*)Xh + off) = *(uint2*)hs;
            *(uint2*)((char*)Xl + off) = *(uint2*)ls;
        }
    }
    __syncthreads();

    f32x4 acc0 = {0.f, 0.f, 0.f, 0.f}, acc1 = acc0;
    {
        const int abase = (mq * 16 + il) * 512;
        const int swz = (il & 7) << 4;
        const short8* Wh8 = (const short8*)Whp;
        const short8* Wl8 = (const short8*)Wlp;
        const int nb = no * 32 + il;
        #pragma unroll
        for (int kc = 0; kc < 8; ++kc) {
            const int ab = abase + ((kc * 64 + jg * 16) ^ swz);
            short8 Ah = *(const short8*)((const char*)Xh + ab);
            short8 Al = *(const short8*)((const char*)Xl + ab);
            const int pidx = (kc * 4 + jg) * 256 + nb;
            short8 Bh0 = Wh8[pidx],      Bl0 = Wl8[pidx];
            short8 Bh1 = Wh8[pidx + 16], Bl1 = Wl8[pidx + 16];
            acc0 = __builtin_amdgcn_mfma_f32_16x16x32_bf16(Ah, Bh0, acc0, 0, 0, 0);
            acc1 = __builtin_amdgcn_mfma_f32_16x16x32_bf16(Ah, Bh1, acc1, 0, 0, 0);
            acc0 = __builtin_amdgcn_mfma_f32_16x16x32_bf16(Ah, Bl0, acc0, 0, 0, 0);
            acc1 = __builtin_amdgcn_mfma_f32_16x16x32_bf16(Ah, Bl1, acc1, 0, 0, 0);
            acc0 = __builtin_amdgcn_mfma_f32_16x16x32_bf16(Al, Bh0, acc0, 0, 0, 0);
            acc1 = __builtin_amdgcn_mfma_f32_16x16x32_bf16(Al, Bh1, acc1, 0, 0, 0);
        }
    }

    const int c0 = no * 32 + il, c1 = c0 + 16;
    const float bia0 = bias[c0], bia1 = bias[c1];
    const int hh = no >> 1;
    const int cc0 = c0 & 63, cc1 = c1 & 63;
    const float as0 = a[hh * 128 + cc0],      as1 = a[hh * 128 + cc1];
    const float ad0 = a[hh * 128 + 64 + cc0], ad1 = a[hh * 128 + 64 + cc1];

    float v0[4], v1[4], psrc[4], pdst[4];
    #pragma unroll
    for (int r = 0; r < 4; ++r) {
        v0[r] = acc0[r] + bia0;
        v1[r] = acc1[r] + bia1;
        psrc[r] = v0[r] * as0 + v1[r] * as1;
        pdst[r] = v0[r] * ad0 + v1[r] * ad1;
    }
    #pragma unroll
    for (int off = 8; off >= 1; off >>= 1) {
        #pragma unroll
        for (int r = 0; r < 4; ++r) {
            psrc[r] += __shfl_xor(psrc[r], off);
            pdst[r] += __shfl_xor(pdst[r], off);
        }
    }
    __syncthreads();   // all waves done reading Xh/Xl

    unsigned short* hp = Xh;
    #pragma unroll
    for (int r = 0; r < 4; ++r) {
        int m = mq * 16 + 4 * jg + r;
        int base = (m >> 3) * 128 + (m & 7);
        hp[(c0 >> 6) * 2048 + ((c0 & 63) >> 4) * 512 + base + (c0 & 15) * 8] = f2bf(v0[r]);
        hp[(c1 >> 6) * 2048 + ((c1 & 63) >> 4) * 512 + base + (c1 & 15) * 8] = f2bf(v1[r]);
    }
    if (il == 0) {
        #pragma unroll
        for (int r = 0; r < 4; ++r) {
            lsP[0][no][mq][4 * jg + r] = psrc[r];
            lsP[1][no][mq][4 * jg + r] = pdst[r];
        }
    }
    __syncthreads();

    {
        uint4* dst4 = (uint4*)(hbf_p + (size_t)(b * 32 + tj) * 8192);
        dst4[tid] = ((const uint4*)hp)[tid];
    }
    if (tid < 256) {
        int sd = tid >> 7, rem = tid & 127, h2 = rem >> 5, m = rem & 31;
        float v = lsP[sd][2 * h2][m >> 4][m & 15] + lsP[sd][2 * h2 + 1][m >> 4][m & 15];
        float* dst = sd ? ldst_t : lsrc_t;
        dst[((size_t)b * HH + h2) * NN + tj * 32 + m] = v;
    }
}

// ---------------- Kernel 2: masked softmax attention, PV via MFMA, LDS-resident -----
// grid 256 x 1024thr (1 block/CU). b = bid&7, h = (bid>>3)&3, i0 = (bid>>5)*128.
// wave = (rg = wv>>2: 32 rows, jq = wv&3: 8 panels). Each 4KB c-frag read feeds
// 8 MFMAs (2 rowgroups) -> block LDS traffic 512 KB. Truncating bf16 cvt for P.
// Epilogue: 2-phase RMW (jq0/1 '=' to separate buffers, jq2/3 '+=').
__global__ __launch_bounds__(1024, 1) void k2_attn(
    const unsigned short* __restrict__ hbf_p, const unsigned int* __restrict__ bmG,
    const float* __restrict__ lsrc_t, const float* __restrict__ ldst_t,
    float* __restrict__ out)
{
    __shared__ __align__(16) char smem[151808];
    // [0, 131072)        hS: head panels, short8 idx tj*256 + cs*64 + l  (epi: red[2][128][68] f32)
    // [131072, 147712)   bmS: u32 [32 tj][130 pad]
    // [147712, 151808)   ldstS: f32 [1024]
    __shared__ float lsumS[4][4][32];     // [jq][rg][row32]

    unsigned short* hS  = (unsigned short*)smem;
    unsigned int*  bmS  = (unsigned int*)(smem + 131072);
    float*        ldstS = (float*)(smem + 147712);

    const int bid = blockIdx.x;
    const int b  = bid & 7;
    const int h  = (bid >> 3) & 3;
    const int i0 = (bid >> 5) * 128;
    const int tid = threadIdx.x;
    const int wv = tid >> 6, l = tid & 63, il = l & 15, jg = l >> 4;
    const int rg = wv >> 2, jq = wv & 3;

    // ---- stage head panel-set via global_load_lds (local L2) ----
    {
        #pragma unroll
        for (int k = 0; k < 2; ++k) {
            const int tj = wv * 2 + k;
            #pragma unroll
            for (int cs = 0; cs < 4; ++cs) {
                gl_lds16(hbf_p + ((((size_t)(b * 32 + tj)) * 1024 + h * 256 + cs * 64 + l) << 3),
                         hS + (size_t)(tj * 256 + cs * 64 + l) * 8);
            }
        }
    }
    // ---- stage bitmap [row][word] -> bmS[word][row] ----
    {
        const unsigned int* bsrc = bmG + ((size_t)(b * NN + i0)) * 32;
        #pragma unroll
        for (int k = 0; k < 4; ++k) {
            int idx = k * 1024 + tid;          // 0..4095
            int r = idx >> 5, w = idx & 31;
            bmS[w * 130 + r] = bsrc[idx];
        }
    }
    // ---- stage ldst table for this head ----
    if (tid < 256)
        ((float4*)ldstS)[tid] = ((const float4*)(ldst_t + ((size_t)(b * HH + h)) * NN))[tid];

    const float* lsrc_b = lsrc_t + ((size_t)(b * HH + h)) * NN + i0 + rg * 32;
    const float lsv0 = lsrc_b[il];
    const float lsv1 = lsrc_b[16 + il];

    __syncthreads();   // staging drained (gl_lds vmcnt included)

    // ---- mx = max over all j of ldst[h] (valid softmax shift: lrelu monotone) ----
    float mx = -3.4e38f;
    #pragma unroll
    for (int jt = 0; jt < 16; ++jt) mx = fmaxf(mx, ldstS[jt * 64 + l]);
    #pragma unroll
    for (int off = 32; off >= 1; off >>= 1) mx = fmaxf(mx, __shfl_xor(mx, off));
    float mr0, mr1;
    { float t_ = lsv0 + mx; mr0 = fmaxf(t_, ALPHA_C * t_); }
    { float t_ = lsv1 + mx; mr1 = fmaxf(t_, ALPHA_C * t_); }
    float ls0 = 0.f, ls1 = 0.f;

    f32x4 z4 = {0.f,0.f,0.f,0.f};
    f32x4 a00 = z4, a01 = z4, a02 = z4, a03 = z4;   // rows rg*32..+15
    f32x4 a10 = z4, a11 = z4, a12 = z4, a13 = z4;   // rows rg*32+16..+31

    const short8* hS8 = (const short8*)hS;

    // ---- hot loop: 8 panels, pure LDS + VALU + MFMA; c-frags reused by 2 rowgroups ----
    #pragma unroll 2
    for (int t = 0; t < 8; ++t) {
        const int tj = jq * 8 + t;
        short8 c0 = hS8[tj * 256 +   0 + l];
        short8 c1 = hS8[tj * 256 +  64 + l];
        short8 c2 = hS8[tj * 256 + 128 + l];
        short8 c3 = hS8[tj * 256 + 192 + l];
        const unsigned int bw0 = bmS[tj * 130 + rg * 32 + il] >> (jg * 8);
        const unsigned int bw1 = bmS[tj * 130 + rg * 32 + 16 + il] >> (jg * 8);
        const float4 dA = *(const float4*)(ldstS + tj * 32 + jg * 8);
        const float4 dB = *(const float4*)(ldstS + tj * 32 + jg * 8 + 4);

        short8 af0, af1;
        #define PELEM(AF, E, DV, BWV, LSV, MR, LS) {             \
            float s_ = (LSV) + (DV);                             \
            s_ = fmaxf(s_, ALPHA_C * s_);                        \
            float p_ = __expf(s_ - (MR));                        \
            p_ = ((BWV >> (E)) & 1u) ? p_ : 0.f;                 \
            LS += p_;                                            \
            AF[E] = (short)(__float_as_uint(p_) >> 16); }
        PELEM(af0, 0, dA.x, bw0, lsv0, mr0, ls0)
        PELEM(af0, 1, dA.y, bw0, lsv0, mr0, ls0)
        PELEM(af0, 2, dA.z, bw0, lsv0, mr0, ls0)
        PELEM(af0, 3, dA.w, bw0, lsv0, mr0, ls0)
        PELEM(af0, 4, dB.x, bw0, lsv0, mr0, ls0)
        PELEM(af0, 5, dB.y, bw0, lsv0, mr0, ls0)
        PELEM(af0, 6, dB.z, bw0, lsv0, mr0, ls0)
        PELEM(af0, 7, dB.w, bw0, lsv0, mr0, ls0)
        PELEM(af1, 0, dA.x, bw1, lsv1, mr1, ls1)
        PELEM(af1, 1, dA.y, bw1, lsv1, mr1, ls1)
        PELEM(af1, 2, dA.z, bw1, lsv1, mr1, ls1)
        PELEM(af1, 3, dA.w, bw1, lsv1, mr1, ls1)
        PELEM(af1, 4, dB.x, bw1, lsv1, mr1, ls1)
        PELEM(af1, 5, dB.y, bw1, lsv1, mr1, ls1)
        PELEM(af1, 6, dB.z, bw1, lsv1, mr1, ls1)
        PELEM(af1, 7, dB.w, bw1, lsv1, mr1, ls1)
        #undef PELEM

        a00 = __builtin_amdgcn_mfma_f32_16x16x32_bf16(af0, c0, a00, 0, 0, 0);
        a01 = __builtin_amdgcn_mfma_f32_16x16x32_bf16(af0, c1, a01, 0, 0, 0);
        a02 = __builtin_amdgcn_mfma_f32_16x16x32_bf16(af0, c2, a02, 0, 0, 0);
        a03 = __builtin_amdgcn_mfma_f32_16x16x32_bf16(af0, c3, a03, 0, 0, 0);
        a10 = __builtin_amdgcn_mfma_f32_16x16x32_bf16(af1, c0, a10, 0, 0, 0);
        a11 = __builtin_amdgcn_mfma_f32_16x16x32_bf16(af1, c1, a11, 0, 0, 0);
        a12 = __builtin_amdgcn_mfma_f32_16x16x32_bf16(af1, c2, a12, 0, 0, 0);
        a13 = __builtin_amdgcn_mfma_f32_16x16x32_bf16(af1, c3, a13, 0, 0, 0);
    }

    // ---- lsum partials (this jq): reduce over jg, stash ----
    ls0 += __shfl_xor(ls0, 16); ls0 += __shfl_xor(ls0, 32);
    ls1 += __shfl_xor(ls1, 16); ls1 += __shfl_xor(ls1, 32);
    if (l < 16) {
        lsumS[jq][rg][il] = ls0;
        lsumS[jq][rg][16 + il] = ls1;
    }
    __syncthreads();   // hot-loop LDS reads done; red may overlay hS

    // ---- 2-phase RMW over jq into red[2][128 rows][68 pad] ----
    float* red0 = (float*)smem;
    float* red1 = red0 + 128 * 68;
    {
        float* rb = (jq & 1) ? red1 : red0;
        const int rbase = rg * 32 + 4 * jg;
        #define STROW(ACC, ROFF, CS, OP) {                                   \
            rb[(rbase + (ROFF) + 0) * 68 + (CS) * 16 + il] OP ACC[0];        \
            rb[(rbase + (ROFF) + 1) * 68 + (CS) * 16 + il] OP ACC[1];        \
            rb[(rbase + (ROFF) + 2) * 68 + (CS) * 16 + il] OP ACC[2];        \
            rb[(rbase + (ROFF) + 3) * 68 + (CS) * 16 + il] OP ACC[3]; }
        #define STOREALL(OP) {                                               \
            STROW(a00, 0, 0, OP) STROW(a01, 0, 1, OP)                        \
            STROW(a02, 0, 2, OP) STROW(a03, 0, 3, OP)                        \
            STROW(a10, 16, 0, OP) STROW(a11, 16, 1, OP)                      \
            STROW(a12, 16, 2, OP) STROW(a13, 16, 3, OP) }
        if (jq < 2) STOREALL(=)
        __syncthreads();
        if (jq >= 2) STOREALL(+=)
        __syncthreads();
        #undef STROW
        #undef STOREALL
    }

    // ---- final: sum red pair, normalize, float4 store ----
    #pragma unroll
    for (int pass = 0; pass < 2; ++pass) {
        int row = pass * 64 + (tid >> 4);
        int c4  = tid & 15;
        float4 v0 = *(const float4*)(red0 + row * 68 + c4 * 4);
        float4 v1 = *(const float4*)(red1 + row * 68 + c4 * 4);
        float ls = lsumS[0][row >> 5][row & 31] + lsumS[1][row >> 5][row & 31]
                 + lsumS[2][row >> 5][row & 31] + lsumS[3][row >> 5][row & 31];
        float inv = 1.0f / ls;
        float4 o = make_float4((v0.x + v1.x) * inv, (v0.y + v1.y) * inv,
                               (v0.z + v1.z) * inv, (v0.w + v1.w) * inv);
        *(float4*)(out + ((size_t)(b * NN + i0 + row)) * COUT + h * 64 + c4 * 4) = o;
    }
}

extern "C" void kernel_launch(void* const* d_in, const int* in_sizes, int n_in,
                              void* d_out, int out_size, void* d_ws, size_t ws_size,
                              hipStream_t stream) {
    const float* X    = (const float*)d_in[0];
    const int*   adj  = (const int*)  d_in[1];
    const float* W    = (const float*)d_in[2];
    const float* bias = (const float*)d_in[3];
    const float* a    = (const float*)d_in[4];
    float* out = (float*)d_out;

    unsigned short* hbf_p = (unsigned short*)d_ws;                  // 8*32 panels, 4 MB
    float* lsrc_t = (float*)(hbf_p + (size_t)BN * 32 * 8192);       // [b][h][n]
    float* ldst_t = lsrc_t + (size_t)BN * HH * NN;
    unsigned short* Whp = (unsigned short*)(ldst_t + (size_t)BN * HH * NN);  // 128 KB
    unsigned short* Wlp = Whp + 65536;                                        // 128 KB
    unsigned int*   bmG = (unsigned int*)(Wlp + 65536);                       // 1 MB bitmap

    kprep<<<2048 + 32, 256, 0, stream>>>(W, adj, Whp, Wlp, bmG);
    k1_gemm<<<256, 1024, 0, stream>>>(X, bias, a, Whp, Wlp, hbf_p, lsrc_t, ldst_t);
    k2_attn<<<256, 1024, 0, stream>>>(hbf_p, bmG, lsrc_t, ldst_t, out);
}